// Round 3
// baseline (1066.689 us; speedup 1.0000x reference)
//
#include <hip/hip_runtime.h>

// SSIM loss over [8,8,3,256,256] fp32.
// One 64-lane wave owns an 8-row band of one 256x256 plane; 4 waves per
// 256-thread workgroup (occupancy: 1-wave workgroups starved the CU at
// ~6 waves resident -> VALUBusy 47%). Vertical 11-tap Gaussian via a
// register ring with STATIC mod-11 indexing (full unroll, no shift movs);
// horizontal 11-tap via cross-lane __shfl. No LDS, no barriers.

#define WSZ 11
#define RAD 5
#define IMH 256
#define IMW 256
#define BAND 8
#define NBANDS (IMH / BAND)     // 32
#define NPLANES 192             // 8*8*3
#define NPIXF (192.0f * 256.0f * 256.0f)
#define NSLOTS 256

__device__ __forceinline__ float clip01(float v) {
    return fminf(fmaxf(v, 0.f), 1.f);
}

__global__ __launch_bounds__(256, 4) void ssim_band_kernel(
    const float* __restrict__ pred,
    const float* __restrict__ targ,
    float* __restrict__ accum)
{
    const int lane = threadIdx.x & 63;
    const int wv = threadIdx.x >> 6;               // 0..3
    const int bg = blockIdx.x * 4 + wv;            // global band id
    const int plane = bg >> 5;                     // 32 bands per plane
    const int band = bg & 31;
    const int r0 = band * BAND;

    const float4* __restrict__ pp =
        (const float4*)(pred + (size_t)plane * (IMH * IMW));
    const float4* __restrict__ tp =
        (const float4*)(targ + (size_t)plane * (IMH * IMW));

    // Gaussian weights (match reference: exp / (sum + 1e-12))
    float w[WSZ];
    {
        float s = 0.f;
#pragma unroll
        for (int i = 0; i < WSZ; ++i) {
            float c = (float)(i - RAD);
            w[i] = expf(-(c * c) / (2.f * 1.5f * 1.5f));
            s += w[i];
        }
        float inv = 1.f / (s + 1e-12f);
#pragma unroll
        for (int i = 0; i < WSZ; ++i) w[i] *= inv;
    }

    // Register ring: 11 rows x {x,y} x 4 cols/lane, clipped.
    float X[WSZ][4], Y[WSZ][4];

    // Preload rows r0-5 .. r0+4 into slots 0..9 (zero pad above image).
#pragma unroll
    for (int j = 0; j < 10; ++j) {
        const int r = r0 - RAD + j;                // max 252, always < 256
        float4 a = make_float4(0.f, 0.f, 0.f, 0.f);
        float4 c = a;
        if (r >= 0) { a = pp[r * 64 + lane]; c = tp[r * 64 + lane]; }
        X[j][0] = clip01(a.x); X[j][1] = clip01(a.y);
        X[j][2] = clip01(a.z); X[j][3] = clip01(a.w);
        Y[j][0] = clip01(c.x); Y[j][1] = clip01(c.y);
        Y[j][2] = clip01(c.z); Y[j][3] = clip01(c.w);
    }

    const float C1 = 1e-4f, C2 = 9e-4f;
    float lsum = 0.f;

#pragma unroll
    for (int i = 0; i < BAND; ++i) {
        // Newest row r0+5+i -> static ring slot (10+i)%11.
        {
            const int slot = (10 + i) % 11;
            const int r = r0 + RAD + i;
            float4 a = make_float4(0.f, 0.f, 0.f, 0.f);
            float4 c = a;
            if (r < IMH) { a = pp[r * 64 + lane]; c = tp[r * 64 + lane]; }
            X[slot][0] = clip01(a.x); X[slot][1] = clip01(a.y);
            X[slot][2] = clip01(a.z); X[slot][3] = clip01(a.w);
            Y[slot][0] = clip01(c.x); Y[slot][1] = clip01(c.y);
            Y[slot][2] = clip01(c.z); Y[slot][3] = clip01(c.w);
        }

        // Vertical pass: 5 channels x 4 cols (static ring indices).
        float vd[5][4];
#pragma unroll
        for (int j = 0; j < 4; ++j) {
            vd[0][j] = 0.f; vd[1][j] = 0.f; vd[2][j] = 0.f;
            vd[3][j] = 0.f; vd[4][j] = 0.f;
        }
#pragma unroll
        for (int k = 0; k < WSZ; ++k) {
            const int slot = (i + k) % 11;
            const float wk = w[k];
#pragma unroll
            for (int j = 0; j < 4; ++j) {
                const float x = X[slot][j], y = Y[slot][j];
                const float wx = wk * x, wy = wk * y;
                vd[0][j] += wx;
                vd[1][j] += wy;
                vd[2][j] = fmaf(wx, x, vd[2][j]);
                vd[3][j] = fmaf(wy, y, vd[3][j]);
                vd[4][j] = fmaf(wx, y, vd[4][j]);
            }
        }

        // Horizontal pass per channel via shuffles; window = cols c0-5..c0+8.
        float hf[5][4];
#pragma unroll
        for (int ch = 0; ch < 5; ++ch) {
            float wnd[14];
            wnd[5] = vd[ch][0]; wnd[6] = vd[ch][1];
            wnd[7] = vd[ch][2]; wnd[8] = vd[ch][3];
            // branchless zero-padding at image edges (cndmask)
            wnd[0]  = (lane >= 2)  ? __shfl_up(vd[ch][3], 2, 64) : 0.f;
            wnd[1]  = (lane >= 1)  ? __shfl_up(vd[ch][0], 1, 64) : 0.f;
            wnd[2]  = (lane >= 1)  ? __shfl_up(vd[ch][1], 1, 64) : 0.f;
            wnd[3]  = (lane >= 1)  ? __shfl_up(vd[ch][2], 1, 64) : 0.f;
            wnd[4]  = (lane >= 1)  ? __shfl_up(vd[ch][3], 1, 64) : 0.f;
            wnd[9]  = (lane <= 62) ? __shfl_down(vd[ch][0], 1, 64) : 0.f;
            wnd[10] = (lane <= 62) ? __shfl_down(vd[ch][1], 1, 64) : 0.f;
            wnd[11] = (lane <= 62) ? __shfl_down(vd[ch][2], 1, 64) : 0.f;
            wnd[12] = (lane <= 62) ? __shfl_down(vd[ch][3], 1, 64) : 0.f;
            wnd[13] = (lane <= 61) ? __shfl_down(vd[ch][0], 2, 64) : 0.f;
#pragma unroll
            for (int j = 0; j < 4; ++j) {
                float a = 0.f;
#pragma unroll
                for (int k = 0; k < WSZ; ++k)
                    a = fmaf(w[k], wnd[j + k], a);
                hf[ch][j] = a;
            }
        }

        // SSIM for 4 pixels.
#pragma unroll
        for (int j = 0; j < 4; ++j) {
            const float mx = hf[0][j], my = hf[1][j];
            const float mx2 = mx * mx, my2 = my * my, mxy = mx * my;
            const float vx = fmaxf(hf[2][j] - mx2, 0.f);
            const float vy = fmaxf(hf[3][j] - my2, 0.f);
            const float vxy = hf[4][j] - mxy;
            const float num = (2.f * mxy + C1) * (2.f * vxy + C2);
            const float den = (mx2 + my2 + C1) * (vx + vy + C2) + 1e-8f;
            lsum += num * __builtin_amdgcn_rcpf(den);
        }
    }

    // Wave reduction (64 lanes), one atomic per wave into spread slots.
#pragma unroll
    for (int off = 32; off > 0; off >>= 1)
        lsum += __shfl_xor(lsum, off, 64);
    if (lane == 0)
        atomicAdd(&accum[bg & (NSLOTS - 1)], lsum);
}

__global__ void ssim_finalize(const float* __restrict__ accum,
                              float* __restrict__ out)
{
    const int l = threadIdx.x;  // 64 threads
    float s = accum[l] + accum[l + 64] + accum[l + 128] + accum[l + 192];
#pragma unroll
    for (int off = 32; off > 0; off >>= 1)
        s += __shfl_xor(s, off, 64);
    if (l == 0) out[0] = 1.0f - s / NPIXF;
}

extern "C" void kernel_launch(void* const* d_in, const int* in_sizes, int n_in,
                              void* d_out, int out_size, void* d_ws, size_t ws_size,
                              hipStream_t stream) {
    const float* pred = (const float*)d_in[0];
    const float* targ = (const float*)d_in[1];
    float* out = (float*)d_out;
    float* acc = (float*)d_ws;

    hipMemsetAsync(acc, 0, NSLOTS * sizeof(float), stream);
    // 192 planes * 32 bands = 6144 waves = 1536 blocks of 4 waves
    ssim_band_kernel<<<NPLANES * NBANDS / 4, 256, 0, stream>>>(pred, targ, acc);
    ssim_finalize<<<1, 64, 0, stream>>>(acc, out);
}

// Round 4
// 207.041 us; speedup vs baseline: 5.1521x; 5.1521x over previous
//
#include <hip/hip_runtime.h>

// SSIM loss over [8,8,3,256,256] fp32.
// R2 body (rolled row loop + register ring shift: 116 VGPR, no spills)
// + 4 waves per 256-thread workgroup (R2 was latency-bound at 20% occupancy
// with 1-wave workgroups). NO min-wave launch bound: R3's (256,4) cap +
// full unroll spilled the ring to scratch (959 MB WRITE_SIZE, 9x slower).

#define WSZ 11
#define RAD 5
#define IMH 256
#define IMW 256
#define BAND 8
#define NBANDS (IMH / BAND)     // 32
#define NPLANES 192             // 8*8*3
#define NPIXF (192.0f * 256.0f * 256.0f)
#define NSLOTS 256

__device__ __forceinline__ float clip01(float v) {
    return fminf(fmaxf(v, 0.f), 1.f);
}

__global__ __launch_bounds__(256) void ssim_band_kernel(
    const float* __restrict__ pred,
    const float* __restrict__ targ,
    float* __restrict__ accum)
{
    const int lane = threadIdx.x & 63;
    const int wv = threadIdx.x >> 6;               // 0..3
    const int bg = blockIdx.x * 4 + wv;            // global band id
    const int plane = bg >> 5;                     // 32 bands per plane
    const int band = bg & 31;
    const int r0 = band * BAND;

    const float4* __restrict__ pp =
        (const float4*)(pred + (size_t)plane * (IMH * IMW));
    const float4* __restrict__ tp =
        (const float4*)(targ + (size_t)plane * (IMH * IMW));

    // Gaussian weights (match reference: exp / (sum + 1e-12))
    float w[WSZ];
    {
        float s = 0.f;
#pragma unroll
        for (int i = 0; i < WSZ; ++i) {
            float c = (float)(i - RAD);
            w[i] = expf(-(c * c) / (2.f * 1.5f * 1.5f));
            s += w[i];
        }
        float inv = 1.f / (s + 1e-12f);
#pragma unroll
        for (int i = 0; i < WSZ; ++i) w[i] *= inv;
    }

    // Register ring: rows r-5..r+5, clipped x and y, 4 cols per lane.
    float X[WSZ][4], Y[WSZ][4];

    // Preload rows r0-5 .. r0+4 into slots 0..9 (zero pad above image).
#pragma unroll
    for (int j = 0; j < 10; ++j) {
        const int r = r0 - RAD + j;                // max 252, always < 256
        float4 a = make_float4(0.f, 0.f, 0.f, 0.f);
        float4 c = a;
        if (r >= 0) { a = pp[r * 64 + lane]; c = tp[r * 64 + lane]; }
        X[j][0] = clip01(a.x); X[j][1] = clip01(a.y);
        X[j][2] = clip01(a.z); X[j][3] = clip01(a.w);
        Y[j][0] = clip01(c.x); Y[j][1] = clip01(c.y);
        Y[j][2] = clip01(c.z); Y[j][3] = clip01(c.w);
    }

    const float C1 = 1e-4f, C2 = 9e-4f;
    float lsum = 0.f;

#pragma unroll 1
    for (int i = 0; i < BAND; ++i) {
        // Load newest row (r0+5+i) into slot 10 (zero pad below image).
        {
            const int r = r0 + RAD + i;
            float4 a = make_float4(0.f, 0.f, 0.f, 0.f);
            float4 c = a;
            if (r < IMH) { a = pp[r * 64 + lane]; c = tp[r * 64 + lane]; }
            X[10][0] = clip01(a.x); X[10][1] = clip01(a.y);
            X[10][2] = clip01(a.z); X[10][3] = clip01(a.w);
            Y[10][0] = clip01(c.x); Y[10][1] = clip01(c.y);
            Y[10][2] = clip01(c.z); Y[10][3] = clip01(c.w);
        }

        // Vertical pass: 5 channels x 4 cols.
        float vd[5][4];
#pragma unroll
        for (int j = 0; j < 4; ++j) {
            vd[0][j] = 0.f; vd[1][j] = 0.f; vd[2][j] = 0.f;
            vd[3][j] = 0.f; vd[4][j] = 0.f;
        }
#pragma unroll
        for (int k = 0; k < WSZ; ++k) {
            const float wk = w[k];
#pragma unroll
            for (int j = 0; j < 4; ++j) {
                const float x = X[k][j], y = Y[k][j];
                const float wx = wk * x, wy = wk * y;
                vd[0][j] += wx;
                vd[1][j] += wy;
                vd[2][j] = fmaf(wx, x, vd[2][j]);
                vd[3][j] = fmaf(wy, y, vd[3][j]);
                vd[4][j] = fmaf(wx, y, vd[4][j]);
            }
        }

        // Horizontal pass per channel via shuffles; window = cols c0-5..c0+8.
        float hf[5][4];
#pragma unroll
        for (int ch = 0; ch < 5; ++ch) {
            float wnd[14];
            wnd[5] = vd[ch][0]; wnd[6] = vd[ch][1];
            wnd[7] = vd[ch][2]; wnd[8] = vd[ch][3];
            // branchless zero-padding at image edges (cndmask)
            wnd[0]  = (lane >= 2)  ? __shfl_up(vd[ch][3], 2, 64) : 0.f;
            wnd[1]  = (lane >= 1)  ? __shfl_up(vd[ch][0], 1, 64) : 0.f;
            wnd[2]  = (lane >= 1)  ? __shfl_up(vd[ch][1], 1, 64) : 0.f;
            wnd[3]  = (lane >= 1)  ? __shfl_up(vd[ch][2], 1, 64) : 0.f;
            wnd[4]  = (lane >= 1)  ? __shfl_up(vd[ch][3], 1, 64) : 0.f;
            wnd[9]  = (lane <= 62) ? __shfl_down(vd[ch][0], 1, 64) : 0.f;
            wnd[10] = (lane <= 62) ? __shfl_down(vd[ch][1], 1, 64) : 0.f;
            wnd[11] = (lane <= 62) ? __shfl_down(vd[ch][2], 1, 64) : 0.f;
            wnd[12] = (lane <= 62) ? __shfl_down(vd[ch][3], 1, 64) : 0.f;
            wnd[13] = (lane <= 61) ? __shfl_down(vd[ch][0], 2, 64) : 0.f;
#pragma unroll
            for (int j = 0; j < 4; ++j) {
                float a = 0.f;
#pragma unroll
                for (int k = 0; k < WSZ; ++k)
                    a = fmaf(w[k], wnd[j + k], a);
                hf[ch][j] = a;
            }
        }

        // SSIM for 4 pixels.
#pragma unroll
        for (int j = 0; j < 4; ++j) {
            const float mx = hf[0][j], my = hf[1][j];
            const float mx2 = mx * mx, my2 = my * my, mxy = mx * my;
            const float vx = fmaxf(hf[2][j] - mx2, 0.f);
            const float vy = fmaxf(hf[3][j] - my2, 0.f);
            const float vxy = hf[4][j] - mxy;
            const float num = (2.f * mxy + C1) * (2.f * vxy + C2);
            const float den = (mx2 + my2 + C1) * (vx + vy + C2) + 1e-8f;
            lsum += num * __builtin_amdgcn_rcpf(den);
        }

        // Shift ring down by one row.
#pragma unroll
        for (int k = 0; k < 10; ++k) {
#pragma unroll
            for (int j = 0; j < 4; ++j) {
                X[k][j] = X[k + 1][j];
                Y[k][j] = Y[k + 1][j];
            }
        }
    }

    // Wave reduction (64 lanes), one atomic per wave into spread slots.
#pragma unroll
    for (int off = 32; off > 0; off >>= 1)
        lsum += __shfl_xor(lsum, off, 64);
    if (lane == 0)
        atomicAdd(&accum[bg & (NSLOTS - 1)], lsum);
}

__global__ void ssim_finalize(const float* __restrict__ accum,
                              float* __restrict__ out)
{
    const int l = threadIdx.x;  // 64 threads
    float s = accum[l] + accum[l + 64] + accum[l + 128] + accum[l + 192];
#pragma unroll
    for (int off = 32; off > 0; off >>= 1)
        s += __shfl_xor(s, off, 64);
    if (l == 0) out[0] = 1.0f - s / NPIXF;
}

extern "C" void kernel_launch(void* const* d_in, const int* in_sizes, int n_in,
                              void* d_out, int out_size, void* d_ws, size_t ws_size,
                              hipStream_t stream) {
    const float* pred = (const float*)d_in[0];
    const float* targ = (const float*)d_in[1];
    float* out = (float*)d_out;
    float* acc = (float*)d_ws;

    hipMemsetAsync(acc, 0, NSLOTS * sizeof(float), stream);
    // 192 planes * 32 bands = 6144 waves = 1536 blocks of 4 waves
    ssim_band_kernel<<<NPLANES * NBANDS / 4, 256, 0, stream>>>(pred, targ, acc);
    ssim_finalize<<<1, 64, 0, stream>>>(acc, out);
}

// Round 5
// 188.093 us; speedup vs baseline: 5.6711x; 1.1007x over previous
//
#include <hip/hip_runtime.h>

// SSIM loss over [8,8,3,256,256] fp32.
// R2 structure (one 64-lane wave per 8-row band, register ring + shuffles,
// rolled row loop, 6144 single-wave blocks) + ONE change: cross-iteration
// software prefetch of the next row. R2/R4 were latency-bound (VALUBusy
// ~50%): the newest row's global_load was consumed immediately each
// iteration. Pending-register prefetch makes the load one full iteration
// (~1400 cyc) old at its waitcnt. R4 showed occupancy does NOT move with
// workgroup shape (20% either way) — so hide latency in-wave instead.
// Also: partials stored per-block to d_ws (no atomics -> no memset dispatch).

#define WSZ 11
#define RAD 5
#define IMH 256
#define IMW 256
#define BAND 8
#define NBANDS (IMH / BAND)     // 32
#define NPLANES 192             // 8*8*3
#define NBLOCKS (NPLANES * NBANDS)  // 6144
#define NPIXF (192.0f * 256.0f * 256.0f)

__device__ __forceinline__ float clip01(float v) {
    return fminf(fmaxf(v, 0.f), 1.f);
}

__global__ __launch_bounds__(64) void ssim_band_kernel(
    const float* __restrict__ pred,
    const float* __restrict__ targ,
    float* __restrict__ partial)
{
    const int lane = threadIdx.x;          // one wave per block
    const int b = blockIdx.x;
    const int plane = b >> 5;              // 32 bands per plane
    const int band = b & 31;
    const int r0 = band * BAND;

    const float4* __restrict__ pp =
        (const float4*)(pred + (size_t)plane * (IMH * IMW));
    const float4* __restrict__ tp =
        (const float4*)(targ + (size_t)plane * (IMH * IMW));

    // Gaussian weights (match reference: exp / (sum + 1e-12))
    float w[WSZ];
    {
        float s = 0.f;
#pragma unroll
        for (int i = 0; i < WSZ; ++i) {
            float c = (float)(i - RAD);
            w[i] = expf(-(c * c) / (2.f * 1.5f * 1.5f));
            s += w[i];
        }
        float inv = 1.f / (s + 1e-12f);
#pragma unroll
        for (int i = 0; i < WSZ; ++i) w[i] *= inv;
    }

    // Register ring: rows r-5..r+5, clipped x and y, 4 cols per lane.
    float X[WSZ][4], Y[WSZ][4];

    // Preload rows r0-5 .. r0+4 into slots 0..9 (zero pad above image).
#pragma unroll
    for (int j = 0; j < 10; ++j) {
        const int r = r0 - RAD + j;                // max 252, always < 256
        float4 a = make_float4(0.f, 0.f, 0.f, 0.f);
        float4 c = a;
        if (r >= 0) { a = pp[r * 64 + lane]; c = tp[r * 64 + lane]; }
        X[j][0] = clip01(a.x); X[j][1] = clip01(a.y);
        X[j][2] = clip01(a.z); X[j][3] = clip01(a.w);
        Y[j][0] = clip01(c.x); Y[j][1] = clip01(c.y);
        Y[j][2] = clip01(c.z); Y[j][3] = clip01(c.w);
    }

    // Prefetch pipeline: pending holds row r0+RAD+i at iteration i entry.
    float4 pa, pc;
    {
        const int r = r0 + RAD;                    // max 253, always < 256
        pa = pp[r * 64 + lane];
        pc = tp[r * 64 + lane];
    }

    const float C1 = 1e-4f, C2 = 9e-4f;
    float lsum = 0.f;

#pragma unroll 1
    for (int i = 0; i < BAND; ++i) {
        // Consume pending (issued last iteration) into slot 10.
        X[10][0] = clip01(pa.x); X[10][1] = clip01(pa.y);
        X[10][2] = clip01(pa.z); X[10][3] = clip01(pa.w);
        Y[10][0] = clip01(pc.x); Y[10][1] = clip01(pc.y);
        Y[10][2] = clip01(pc.z); Y[10][3] = clip01(pc.w);

        // Issue next row's loads (wave-uniform guard, no divergence).
        {
            const int rn = r0 + RAD + i + 1;
            if (rn < IMH) {
                pa = pp[rn * 64 + lane];
                pc = tp[rn * 64 + lane];
            } else {
                pa = make_float4(0.f, 0.f, 0.f, 0.f);
                pc = make_float4(0.f, 0.f, 0.f, 0.f);
            }
        }

        // Vertical pass: 5 channels x 4 cols.
        float vd[5][4];
#pragma unroll
        for (int j = 0; j < 4; ++j) {
            vd[0][j] = 0.f; vd[1][j] = 0.f; vd[2][j] = 0.f;
            vd[3][j] = 0.f; vd[4][j] = 0.f;
        }
#pragma unroll
        for (int k = 0; k < WSZ; ++k) {
            const float wk = w[k];
#pragma unroll
            for (int j = 0; j < 4; ++j) {
                const float x = X[k][j], y = Y[k][j];
                const float wx = wk * x, wy = wk * y;
                vd[0][j] += wx;
                vd[1][j] += wy;
                vd[2][j] = fmaf(wx, x, vd[2][j]);
                vd[3][j] = fmaf(wy, y, vd[3][j]);
                vd[4][j] = fmaf(wx, y, vd[4][j]);
            }
        }

        // Horizontal pass per channel via shuffles; window = cols c0-5..c0+8.
        float hf[5][4];
#pragma unroll
        for (int ch = 0; ch < 5; ++ch) {
            float wnd[14];
            wnd[5] = vd[ch][0]; wnd[6] = vd[ch][1];
            wnd[7] = vd[ch][2]; wnd[8] = vd[ch][3];
            wnd[1] = __shfl_up(vd[ch][0], 1, 64);
            wnd[2] = __shfl_up(vd[ch][1], 1, 64);
            wnd[3] = __shfl_up(vd[ch][2], 1, 64);
            wnd[4] = __shfl_up(vd[ch][3], 1, 64);
            wnd[0] = __shfl_up(vd[ch][3], 2, 64);
            wnd[9]  = __shfl_down(vd[ch][0], 1, 64);
            wnd[10] = __shfl_down(vd[ch][1], 1, 64);
            wnd[11] = __shfl_down(vd[ch][2], 1, 64);
            wnd[12] = __shfl_down(vd[ch][3], 1, 64);
            wnd[13] = __shfl_down(vd[ch][0], 2, 64);
            // zero padding at image edges
            if (lane == 0) {
                wnd[0] = 0.f; wnd[1] = 0.f; wnd[2] = 0.f;
                wnd[3] = 0.f; wnd[4] = 0.f;
            } else if (lane == 1) {
                wnd[0] = 0.f;
            }
            if (lane == 63) {
                wnd[9] = 0.f; wnd[10] = 0.f; wnd[11] = 0.f;
                wnd[12] = 0.f; wnd[13] = 0.f;
            } else if (lane == 62) {
                wnd[13] = 0.f;
            }
#pragma unroll
            for (int j = 0; j < 4; ++j) {
                float a = 0.f;
#pragma unroll
                for (int k = 0; k < WSZ; ++k)
                    a = fmaf(w[k], wnd[j + k], a);
                hf[ch][j] = a;
            }
        }

        // SSIM for 4 pixels.
#pragma unroll
        for (int j = 0; j < 4; ++j) {
            const float mx = hf[0][j], my = hf[1][j];
            const float mx2 = mx * mx, my2 = my * my, mxy = mx * my;
            const float vx = fmaxf(hf[2][j] - mx2, 0.f);
            const float vy = fmaxf(hf[3][j] - my2, 0.f);
            const float vxy = hf[4][j] - mxy;
            const float num = (2.f * mxy + C1) * (2.f * vxy + C2);
            const float den = (mx2 + my2 + C1) * (vx + vy + C2) + 1e-8f;
            lsum += num * __builtin_amdgcn_rcpf(den);
        }

        // Shift ring down by one row.
#pragma unroll
        for (int k = 0; k < 10; ++k) {
#pragma unroll
            for (int j = 0; j < 4; ++j) {
                X[k][j] = X[k + 1][j];
                Y[k][j] = Y[k + 1][j];
            }
        }
    }

    // Wave reduction (64 lanes), one plain store per block (no atomics,
    // no memset dispatch needed).
#pragma unroll
    for (int off = 32; off > 0; off >>= 1)
        lsum += __shfl_xor(lsum, off, 64);
    if (lane == 0)
        partial[b] = lsum;
}

__global__ __launch_bounds__(256) void ssim_finalize(
    const float* __restrict__ partial,
    float* __restrict__ out)
{
    __shared__ float wsum[4];
    const int t = threadIdx.x;  // 256 threads
    float s = 0.f;
    for (int i = t; i < NBLOCKS; i += 256) s += partial[i];
#pragma unroll
    for (int off = 32; off > 0; off >>= 1)
        s += __shfl_xor(s, off, 64);
    const int lane = t & 63, wv = t >> 6;
    if (lane == 0) wsum[wv] = s;
    __syncthreads();
    if (t == 0)
        out[0] = 1.0f - (wsum[0] + wsum[1] + wsum[2] + wsum[3]) / NPIXF;
}

extern "C" void kernel_launch(void* const* d_in, const int* in_sizes, int n_in,
                              void* d_out, int out_size, void* d_ws, size_t ws_size,
                              hipStream_t stream) {
    const float* pred = (const float*)d_in[0];
    const float* targ = (const float*)d_in[1];
    float* out = (float*)d_out;
    float* part = (float*)d_ws;    // 6144 floats = 24 KB scratch

    ssim_band_kernel<<<NBLOCKS, 64, 0, stream>>>(pred, targ, part);
    ssim_finalize<<<1, 256, 0, stream>>>(part, out);
}

// Round 6
// 186.275 us; speedup vs baseline: 5.7264x; 1.0098x over previous
//
#include <hip/hip_runtime.h>

// SSIM loss over [8,8,3,256,256] fp32.
// R5 structure (wave-per-band register ring + shuffles, rolled row loop,
// cross-iteration prefetch, per-block partial stores) with the VALU work
// packed into v_pk_*_f32 (2 fp32 ops/instr, gfx90a+) and BAND=16.
// Evidence: R2/R4/R5 all show VALU busy-time ~49us at ~50% utilization no
// matter the launch shape -> cut instructions, don't reshuffle them.
// R3 scar: keep the row loop ROLLED (#pragma unroll 1) or the ring spills.

typedef float v2f __attribute__((ext_vector_type(2)));

#define WSZ 11
#define RAD 5
#define IMH 256
#define IMW 256
#define BAND 16
#define NBANDS (IMH / BAND)         // 16
#define NPLANES 192                 // 8*8*3
#define NBLOCKS (NPLANES * NBANDS)  // 3072
#define NPIXF (192.0f * 256.0f * 256.0f)

// Gaussian(sigma=1.5, ws=11) weights, normalized (matches expf/sum+1e-12
// to ~1e-6 relative; final-scalar impact ~1e-6 vs 1.96e-2 threshold).
#define GW0 0.001028381f
#define GW1 0.007598770f
#define GW2 0.036000770f
#define GW3 0.109360600f
#define GW4 0.213005700f
#define GW5 0.266011790f

__device__ __forceinline__ v2f pk_fma(v2f a, v2f b, v2f c) {
#if __has_builtin(__builtin_elementwise_fma)
    return __builtin_elementwise_fma(a, b, c);
#else
    v2f d;
    asm("v_pk_fma_f32 %0, %1, %2, %3" : "=v"(d) : "v"(a), "v"(b), "v"(c));
    return d;
#endif
}

__device__ __forceinline__ v2f splat2(float s) { return (v2f){s, s}; }

__device__ __forceinline__ v2f clip2(v2f v) {
    v2f r;
    r.x = fminf(fmaxf(v.x, 0.f), 1.f);
    r.y = fminf(fmaxf(v.y, 0.f), 1.f);
    return r;
}

__global__ __launch_bounds__(64) void ssim_band_kernel(
    const float* __restrict__ pred,
    const float* __restrict__ targ,
    float* __restrict__ partial)
{
    const int lane = threadIdx.x;          // one wave per block
    const int b = blockIdx.x;
    const int plane = b >> 4;              // 16 bands per plane
    const int band = b & 15;
    const int r0 = band * BAND;

    const float4* __restrict__ pp =
        (const float4*)(pred + (size_t)plane * (IMH * IMW));
    const float4* __restrict__ tp =
        (const float4*)(targ + (size_t)plane * (IMH * IMW));

    const float w[WSZ] = {GW0, GW1, GW2, GW3, GW4, GW5,
                          GW4, GW3, GW2, GW1, GW0};

    // Register ring: rows r-5..r+5, clipped x and y, 2 v2f (4 cols) per lane.
    v2f X[WSZ][2], Y[WSZ][2];

    // Preload rows r0-5 .. r0+4 into slots 0..9 (zero pad above image).
#pragma unroll
    for (int j = 0; j < 10; ++j) {
        const int r = r0 - RAD + j;                // max 244, always < 256
        float4 a = make_float4(0.f, 0.f, 0.f, 0.f);
        float4 c = a;
        if (r >= 0) { a = pp[r * 64 + lane]; c = tp[r * 64 + lane]; }
        X[j][0] = clip2((v2f){a.x, a.y}); X[j][1] = clip2((v2f){a.z, a.w});
        Y[j][0] = clip2((v2f){c.x, c.y}); Y[j][1] = clip2((v2f){c.z, c.w});
    }

    // Prefetch pipeline: pending holds row r0+RAD+i at iteration i entry.
    float4 pa, pc;
    {
        const int r = r0 + RAD;                    // max 245, always < 256
        pa = pp[r * 64 + lane];
        pc = tp[r * 64 + lane];
    }

    const float C1 = 1e-4f, C2 = 9e-4f;
    float lsum = 0.f;

#pragma unroll 1
    for (int i = 0; i < BAND; ++i) {
        // Consume pending (issued last iteration) into slot 10.
        X[10][0] = clip2((v2f){pa.x, pa.y}); X[10][1] = clip2((v2f){pa.z, pa.w});
        Y[10][0] = clip2((v2f){pc.x, pc.y}); Y[10][1] = clip2((v2f){pc.z, pc.w});

        // Issue next row's loads (wave-uniform guard, no divergence).
        {
            const int rn = r0 + RAD + i + 1;
            if (rn < IMH) {
                pa = pp[rn * 64 + lane];
                pc = tp[rn * 64 + lane];
            } else {
                pa = make_float4(0.f, 0.f, 0.f, 0.f);
                pc = make_float4(0.f, 0.f, 0.f, 0.f);
            }
        }

        // Vertical pass: 5 channels x 2 col-pairs, packed.
        v2f vd[5][2];
#pragma unroll
        for (int p = 0; p < 2; ++p) {
            vd[0][p] = splat2(0.f); vd[1][p] = splat2(0.f);
            vd[2][p] = splat2(0.f); vd[3][p] = splat2(0.f);
            vd[4][p] = splat2(0.f);
        }
#pragma unroll
        for (int k = 0; k < WSZ; ++k) {
            const v2f wk = splat2(w[k]);
#pragma unroll
            for (int p = 0; p < 2; ++p) {
                const v2f x = X[k][p], y = Y[k][p];
                const v2f wx = wk * x, wy = wk * y;
                vd[0][p] += wx;
                vd[1][p] += wy;
                vd[2][p] = pk_fma(wx, x, vd[2][p]);
                vd[3][p] = pk_fma(wy, y, vd[3][p]);
                vd[4][p] = pk_fma(wx, y, vd[4][p]);
            }
        }

        // Horizontal pass per channel via shuffles, packed even/odd taps.
        v2f hf[5][2];
#pragma unroll
        for (int ch = 0; ch < 5; ++ch) {
            const float c0 = vd[ch][0].x, c1 = vd[ch][0].y;
            const float c2 = vd[ch][1].x, c3 = vd[ch][1].y;
            float wnd0, wnd1, wnd2, wnd3, wnd4;
            float wnd9, wnd10, wnd11, wnd12, wnd13;
            wnd1 = __shfl_up(c0, 1, 64);
            wnd2 = __shfl_up(c1, 1, 64);
            wnd3 = __shfl_up(c2, 1, 64);
            wnd4 = __shfl_up(c3, 1, 64);
            wnd0 = __shfl_up(c3, 2, 64);
            wnd9  = __shfl_down(c0, 1, 64);
            wnd10 = __shfl_down(c1, 1, 64);
            wnd11 = __shfl_down(c2, 1, 64);
            wnd12 = __shfl_down(c3, 1, 64);
            wnd13 = __shfl_down(c0, 2, 64);
            if (lane == 0) {
                wnd0 = 0.f; wnd1 = 0.f; wnd2 = 0.f; wnd3 = 0.f; wnd4 = 0.f;
            } else if (lane == 1) {
                wnd0 = 0.f;
            }
            if (lane == 63) {
                wnd9 = 0.f; wnd10 = 0.f; wnd11 = 0.f; wnd12 = 0.f; wnd13 = 0.f;
            } else if (lane == 62) {
                wnd13 = 0.f;
            }
            // Aligned pairs P[j] = {wnd[2j], wnd[2j+1]},
            // shifted pairs O[j] = {wnd[2j+1], wnd[2j+2]}.
            const v2f P0 = {wnd0, wnd1},  P1 = {wnd2, wnd3},
                      P2 = {wnd4, c0},    P3 = {c1, c2},
                      P4 = {c3, wnd9},    P5 = {wnd10, wnd11},
                      P6 = {wnd12, wnd13};
            const v2f O0 = {wnd1, wnd2},  O1 = {wnd3, wnd4},
                      O2 = {c0, c1},      O3 = {c2, c3},
                      O4 = {wnd9, wnd10}, O5 = {wnd11, wnd12};
            // Output pair {cols 4l, 4l+1}: tap k even -> P[k/2], odd -> O[(k-1)/2]
            v2f a0 = splat2(GW0) * P0;
            a0 = pk_fma(splat2(GW1), O0, a0);
            a0 = pk_fma(splat2(GW2), P1, a0);
            a0 = pk_fma(splat2(GW3), O1, a0);
            a0 = pk_fma(splat2(GW4), P2, a0);
            a0 = pk_fma(splat2(GW5), O2, a0);
            a0 = pk_fma(splat2(GW4), P3, a0);
            a0 = pk_fma(splat2(GW3), O3, a0);
            a0 = pk_fma(splat2(GW2), P4, a0);
            a0 = pk_fma(splat2(GW1), O4, a0);
            a0 = pk_fma(splat2(GW0), P5, a0);
            // Output pair {cols 4l+2, 4l+3}: shift source index by one pair.
            v2f a1 = splat2(GW0) * P1;
            a1 = pk_fma(splat2(GW1), O1, a1);
            a1 = pk_fma(splat2(GW2), P2, a1);
            a1 = pk_fma(splat2(GW3), O2, a1);
            a1 = pk_fma(splat2(GW4), P3, a1);
            a1 = pk_fma(splat2(GW5), O3, a1);
            a1 = pk_fma(splat2(GW4), P4, a1);
            a1 = pk_fma(splat2(GW3), O4, a1);
            a1 = pk_fma(splat2(GW2), P5, a1);
            a1 = pk_fma(splat2(GW1), O5, a1);
            a1 = pk_fma(splat2(GW0), P6, a1);
            hf[ch][0] = a0;
            hf[ch][1] = a1;
        }

        // SSIM for 2 col-pairs, packed where possible.
#pragma unroll
        for (int p = 0; p < 2; ++p) {
            const v2f mx = hf[0][p], my = hf[1][p];
            const v2f mx2 = mx * mx, my2 = my * my, mxy = mx * my;
            v2f vx = hf[2][p] - mx2;
            v2f vy = hf[3][p] - my2;
            vx.x = fmaxf(vx.x, 0.f); vx.y = fmaxf(vx.y, 0.f);
            vy.x = fmaxf(vy.x, 0.f); vy.y = fmaxf(vy.y, 0.f);
            const v2f vxy = hf[4][p] - mxy;
            const v2f num = pk_fma(splat2(2.f), mxy, splat2(C1)) *
                            pk_fma(splat2(2.f), vxy, splat2(C2));
            const v2f den = (mx2 + my2 + splat2(C1)) *
                            (vx + vy + splat2(C2)) + splat2(1e-8f);
            lsum += num.x * __builtin_amdgcn_rcpf(den.x);
            lsum += num.y * __builtin_amdgcn_rcpf(den.y);
        }

        // Shift ring down by one row (64-bit moves).
#pragma unroll
        for (int k = 0; k < 10; ++k) {
            X[k][0] = X[k + 1][0]; X[k][1] = X[k + 1][1];
            Y[k][0] = Y[k + 1][0]; Y[k][1] = Y[k + 1][1];
        }
    }

    // Wave reduction (64 lanes), one plain store per block.
#pragma unroll
    for (int off = 32; off > 0; off >>= 1)
        lsum += __shfl_xor(lsum, off, 64);
    if (lane == 0)
        partial[b] = lsum;
}

__global__ __launch_bounds__(256) void ssim_finalize(
    const float* __restrict__ partial,
    float* __restrict__ out)
{
    __shared__ float wsum[4];
    const int t = threadIdx.x;  // 256 threads
    float s = 0.f;
    for (int i = t; i < NBLOCKS; i += 256) s += partial[i];
#pragma unroll
    for (int off = 32; off > 0; off >>= 1)
        s += __shfl_xor(s, off, 64);
    const int lane = t & 63, wv = t >> 6;
    if (lane == 0) wsum[wv] = s;
    __syncthreads();
    if (t == 0)
        out[0] = 1.0f - (wsum[0] + wsum[1] + wsum[2] + wsum[3]) / NPIXF;
}

extern "C" void kernel_launch(void* const* d_in, const int* in_sizes, int n_in,
                              void* d_out, int out_size, void* d_ws, size_t ws_size,
                              hipStream_t stream) {
    const float* pred = (const float*)d_in[0];
    const float* targ = (const float*)d_in[1];
    float* out = (float*)d_out;
    float* part = (float*)d_ws;    // 3072 floats = 12 KB scratch

    ssim_band_kernel<<<NBLOCKS, 64, 0, stream>>>(pred, targ, part);
    ssim_finalize<<<1, 256, 0, stream>>>(part, out);
}

// Round 7
// 174.177 us; speedup vs baseline: 6.1242x; 1.0695x over previous
//
#include <hip/hip_runtime.h>

// SSIM loss over [8,8,3,256,256] fp32.
// R6 structure (wave-per-band register ring + shuffles, rolled row loop,
// prefetch, BAND=16, per-block partial stores) with VOP3P packed fp32
// FORCED via inline asm. Evidence: R6's ext_vector_type arithmetic changed
// VALU busy-time by 0% (51us vs R5's 49us) despite a -35% source-op
// rewrite -> the builtins scalarized. v_pk_{fma,mul,add}_f32 (gfx90a+,
// full-rate) is the real 2x fp32 path.
// R3 scar: keep the row loop ROLLED (#pragma unroll 1) or the ring spills.

typedef float v2f __attribute__((ext_vector_type(2)));

#define WSZ 11
#define RAD 5
#define IMH 256
#define IMW 256
#define BAND 16
#define NBANDS (IMH / BAND)         // 16
#define NPLANES 192                 // 8*8*3
#define NBLOCKS (NPLANES * NBANDS)  // 3072
#define NPIXF (192.0f * 256.0f * 256.0f)

// Gaussian(sigma=1.5, ws=11) weights, normalized.
#define GW0 0.001028381f
#define GW1 0.007598770f
#define GW2 0.036000770f
#define GW3 0.109360600f
#define GW4 0.213005700f
#define GW5 0.266011790f

// --- forced VOP3P packed fp32 (full-rate on CDNA) ---
__device__ __forceinline__ v2f pk_fma(v2f a, v2f b, v2f c) {
    v2f d;
    asm("v_pk_fma_f32 %0, %1, %2, %3" : "=v"(d) : "v"(a), "v"(b), "v"(c));
    return d;
}
__device__ __forceinline__ v2f pk_mul(v2f a, v2f b) {
    v2f d;
    asm("v_pk_mul_f32 %0, %1, %2" : "=v"(d) : "v"(a), "v"(b));
    return d;
}
__device__ __forceinline__ v2f pk_add(v2f a, v2f b) {
    v2f d;
    asm("v_pk_add_f32 %0, %1, %2" : "=v"(d) : "v"(a), "v"(b));
    return d;
}

__device__ __forceinline__ v2f splat2(float s) { return (v2f){s, s}; }

__device__ __forceinline__ v2f clip2(v2f v) {
    v2f r;
    r.x = fminf(fmaxf(v.x, 0.f), 1.f);
    r.y = fminf(fmaxf(v.y, 0.f), 1.f);
    return r;
}

__global__ __launch_bounds__(64) void ssim_band_kernel(
    const float* __restrict__ pred,
    const float* __restrict__ targ,
    float* __restrict__ partial)
{
    const int lane = threadIdx.x;          // one wave per block
    const int b = blockIdx.x;
    const int plane = b >> 4;              // 16 bands per plane
    const int band = b & 15;
    const int r0 = band * BAND;

    const float4* __restrict__ pp =
        (const float4*)(pred + (size_t)plane * (IMH * IMW));
    const float4* __restrict__ tp =
        (const float4*)(targ + (size_t)plane * (IMH * IMW));

    // Packed, loop-invariant weight splats (CSE'd into pinned reg pairs).
    const v2f W0 = splat2(GW0), W1 = splat2(GW1), W2 = splat2(GW2),
              W3 = splat2(GW3), W4 = splat2(GW4), W5 = splat2(GW5);
    const float w[WSZ] = {GW0, GW1, GW2, GW3, GW4, GW5,
                          GW4, GW3, GW2, GW1, GW0};

    // Register ring: rows r-5..r+5, clipped x and y, 2 v2f (4 cols) per lane.
    v2f X[WSZ][2], Y[WSZ][2];

    // Preload rows r0-5 .. r0+4 into slots 0..9 (zero pad above image).
#pragma unroll
    for (int j = 0; j < 10; ++j) {
        const int r = r0 - RAD + j;                // max 244, always < 256
        float4 a = make_float4(0.f, 0.f, 0.f, 0.f);
        float4 c = a;
        if (r >= 0) { a = pp[r * 64 + lane]; c = tp[r * 64 + lane]; }
        X[j][0] = clip2((v2f){a.x, a.y}); X[j][1] = clip2((v2f){a.z, a.w});
        Y[j][0] = clip2((v2f){c.x, c.y}); Y[j][1] = clip2((v2f){c.z, c.w});
    }

    // Prefetch pipeline: pending holds row r0+RAD+i at iteration i entry.
    float4 pa, pc;
    {
        const int r = r0 + RAD;                    // max 245, always < 256
        pa = pp[r * 64 + lane];
        pc = tp[r * 64 + lane];
    }

    const float C1 = 1e-4f, C2 = 9e-4f;
    float lsum = 0.f;

#pragma unroll 1
    for (int i = 0; i < BAND; ++i) {
        // Consume pending (issued last iteration) into slot 10.
        X[10][0] = clip2((v2f){pa.x, pa.y}); X[10][1] = clip2((v2f){pa.z, pa.w});
        Y[10][0] = clip2((v2f){pc.x, pc.y}); Y[10][1] = clip2((v2f){pc.z, pc.w});

        // Issue next row's loads (wave-uniform guard, no divergence).
        {
            const int rn = r0 + RAD + i + 1;
            if (rn < IMH) {
                pa = pp[rn * 64 + lane];
                pc = tp[rn * 64 + lane];
            } else {
                pa = make_float4(0.f, 0.f, 0.f, 0.f);
                pc = make_float4(0.f, 0.f, 0.f, 0.f);
            }
        }

        // Vertical pass: 5 channels x 2 col-pairs, forced v_pk_*.
        v2f vd[5][2];
#pragma unroll
        for (int p = 0; p < 2; ++p) {
            vd[0][p] = splat2(0.f); vd[1][p] = splat2(0.f);
            vd[2][p] = splat2(0.f); vd[3][p] = splat2(0.f);
            vd[4][p] = splat2(0.f);
        }
#pragma unroll
        for (int k = 0; k < WSZ; ++k) {
            const v2f wk = splat2(w[k]);
#pragma unroll
            for (int p = 0; p < 2; ++p) {
                const v2f x = X[k][p], y = Y[k][p];
                const v2f wx = pk_mul(wk, x);
                const v2f wy = pk_mul(wk, y);
                vd[0][p] = pk_add(vd[0][p], wx);
                vd[1][p] = pk_add(vd[1][p], wy);
                vd[2][p] = pk_fma(wx, x, vd[2][p]);
                vd[3][p] = pk_fma(wy, y, vd[3][p]);
                vd[4][p] = pk_fma(wx, y, vd[4][p]);
            }
        }

        // Horizontal pass per channel via shuffles, packed even/odd taps.
        v2f hf[5][2];
#pragma unroll
        for (int ch = 0; ch < 5; ++ch) {
            const float c0 = vd[ch][0].x, c1 = vd[ch][0].y;
            const float c2 = vd[ch][1].x, c3 = vd[ch][1].y;
            float wnd0, wnd1, wnd2, wnd3, wnd4;
            float wnd9, wnd10, wnd11, wnd12, wnd13;
            wnd1 = __shfl_up(c0, 1, 64);
            wnd2 = __shfl_up(c1, 1, 64);
            wnd3 = __shfl_up(c2, 1, 64);
            wnd4 = __shfl_up(c3, 1, 64);
            wnd0 = __shfl_up(c3, 2, 64);
            wnd9  = __shfl_down(c0, 1, 64);
            wnd10 = __shfl_down(c1, 1, 64);
            wnd11 = __shfl_down(c2, 1, 64);
            wnd12 = __shfl_down(c3, 1, 64);
            wnd13 = __shfl_down(c0, 2, 64);
            if (lane == 0) {
                wnd0 = 0.f; wnd1 = 0.f; wnd2 = 0.f; wnd3 = 0.f; wnd4 = 0.f;
            } else if (lane == 1) {
                wnd0 = 0.f;
            }
            if (lane == 63) {
                wnd9 = 0.f; wnd10 = 0.f; wnd11 = 0.f; wnd12 = 0.f; wnd13 = 0.f;
            } else if (lane == 62) {
                wnd13 = 0.f;
            }
            // Aligned pairs P[j] = {wnd[2j], wnd[2j+1]},
            // shifted pairs O[j] = {wnd[2j+1], wnd[2j+2]}.
            const v2f P0 = {wnd0, wnd1},  P1 = {wnd2, wnd3},
                      P2 = {wnd4, c0},    P3 = {c1, c2},
                      P4 = {c3, wnd9},    P5 = {wnd10, wnd11},
                      P6 = {wnd12, wnd13};
            const v2f O0 = {wnd1, wnd2},  O1 = {wnd3, wnd4},
                      O2 = {c0, c1},      O3 = {c2, c3},
                      O4 = {wnd9, wnd10}, O5 = {wnd11, wnd12};
            v2f a0 = pk_mul(W0, P0);
            a0 = pk_fma(W1, O0, a0);
            a0 = pk_fma(W2, P1, a0);
            a0 = pk_fma(W3, O1, a0);
            a0 = pk_fma(W4, P2, a0);
            a0 = pk_fma(W5, O2, a0);
            a0 = pk_fma(W4, P3, a0);
            a0 = pk_fma(W3, O3, a0);
            a0 = pk_fma(W2, P4, a0);
            a0 = pk_fma(W1, O4, a0);
            a0 = pk_fma(W0, P5, a0);
            v2f a1 = pk_mul(W0, P1);
            a1 = pk_fma(W1, O1, a1);
            a1 = pk_fma(W2, P2, a1);
            a1 = pk_fma(W3, O2, a1);
            a1 = pk_fma(W4, P3, a1);
            a1 = pk_fma(W5, O3, a1);
            a1 = pk_fma(W4, P4, a1);
            a1 = pk_fma(W3, O4, a1);
            a1 = pk_fma(W2, P5, a1);
            a1 = pk_fma(W1, O5, a1);
            a1 = pk_fma(W0, P6, a1);
            hf[ch][0] = a0;
            hf[ch][1] = a1;
        }

        // SSIM for 2 col-pairs, packed epilogue.
        const v2f two = splat2(2.f);
        const v2f c1v = splat2(C1), c2v = splat2(C2), epsv = splat2(1e-8f);
#pragma unroll
        for (int p = 0; p < 2; ++p) {
            const v2f mx = hf[0][p], my = hf[1][p];
            const v2f mx2 = pk_mul(mx, mx);
            const v2f my2 = pk_mul(my, my);
            const v2f mxy = pk_mul(mx, my);
            v2f vx = hf[2][p] - mx2;    // scalar sub ok (2 ops)
            v2f vy = hf[3][p] - my2;
            vx.x = fmaxf(vx.x, 0.f); vx.y = fmaxf(vx.y, 0.f);
            vy.x = fmaxf(vy.x, 0.f); vy.y = fmaxf(vy.y, 0.f);
            const v2f vxy = hf[4][p] - mxy;
            const v2f num = pk_mul(pk_fma(two, mxy, c1v),
                                   pk_fma(two, vxy, c2v));
            const v2f den = pk_add(pk_mul(pk_add(pk_add(mx2, my2), c1v),
                                          pk_add(pk_add(vx, vy), c2v)), epsv);
            lsum += num.x * __builtin_amdgcn_rcpf(den.x);
            lsum += num.y * __builtin_amdgcn_rcpf(den.y);
        }

        // Shift ring down by one row (64-bit moves).
#pragma unroll
        for (int k = 0; k < 10; ++k) {
            X[k][0] = X[k + 1][0]; X[k][1] = X[k + 1][1];
            Y[k][0] = Y[k + 1][0]; Y[k][1] = Y[k + 1][1];
        }
    }

    // Wave reduction (64 lanes), one plain store per block.
#pragma unroll
    for (int off = 32; off > 0; off >>= 1)
        lsum += __shfl_xor(lsum, off, 64);
    if (lane == 0)
        partial[b] = lsum;
}

__global__ __launch_bounds__(256) void ssim_finalize(
    const float* __restrict__ partial,
    float* __restrict__ out)
{
    __shared__ float wsum[4];
    const int t = threadIdx.x;  // 256 threads
    float s = 0.f;
    for (int i = t; i < NBLOCKS; i += 256) s += partial[i];
#pragma unroll
    for (int off = 32; off > 0; off >>= 1)
        s += __shfl_xor(s, off, 64);
    const int lane = t & 63, wv = t >> 6;
    if (lane == 0) wsum[wv] = s;
    __syncthreads();
    if (t == 0)
        out[0] = 1.0f - (wsum[0] + wsum[1] + wsum[2] + wsum[3]) / NPIXF;
}

extern "C" void kernel_launch(void* const* d_in, const int* in_sizes, int n_in,
                              void* d_out, int out_size, void* d_ws, size_t ws_size,
                              hipStream_t stream) {
    const float* pred = (const float*)d_in[0];
    const float* targ = (const float*)d_in[1];
    float* out = (float*)d_out;
    float* part = (float*)d_ws;    // 3072 floats = 12 KB scratch

    ssim_band_kernel<<<NBLOCKS, 64, 0, stream>>>(pred, targ, part);
    ssim_finalize<<<1, 256, 0, stream>>>(part, out);
}